// Round 4
// baseline (131.494 us; speedup 1.0000x reference)
//
#include <hip/hip_runtime.h>

#define BB 256
#define TT 256
#define CC 256
#define HH 64

typedef _Float16 half8 __attribute__((ext_vector_type(8)));
typedef _Float16 half4 __attribute__((ext_vector_type(4)));
typedef __fp16 fp16x2 __attribute__((ext_vector_type(2)));
typedef float floatx4 __attribute__((ext_vector_type(4)));
typedef float floatx16 __attribute__((ext_vector_type(16)));

// ---------------------------------------------------------------------------
// prep: blocks 0..63   -> rpeh[i] = (f16) rpe[i]  (rows 0..255)
//       blocks 64..255 -> WT[(w*64+n)][k] = (f16) W_w[k][n]
// ---------------------------------------------------------------------------
__global__ __launch_bounds__(256) void prep(
    const float* __restrict__ rpe,
    const float* __restrict__ Wk, const float* __restrict__ Wq, const float* __restrict__ Wv,
    _Float16* __restrict__ rpeh, _Float16* __restrict__ WT)
{
    const int bid = blockIdx.x, tid = threadIdx.x;
    if (bid < 64) {
        const int i = bid * 256 + tid;
        rpeh[i] = (_Float16)rpe[i];
    } else {
        const int wsel = (bid - 64) >> 6;          // 0=k, 1=q, 2=v
        const int n    = (bid - 64) & 63;
        const float* W = wsel == 0 ? Wk : (wsel == 1 ? Wq : Wv);
        WT[(size_t)(wsel * 64 + n) * 256 + tid] = (_Float16)W[tid * HH + n];
    }
}

// per-tile exp-weight slot pool: pair j = t>>1 shares width V_j
__device__ __forceinline__ int slot_width(int t) {
    const int j = t >> 1;
    return (j < 2) ? 72 : (32 * j + 40);
}
__device__ __forceinline__ int slot_off(int t) {      // halves, rel. to pool
    const int j = t >> 1;
    const int V = (j < 2) ? 72 : (32 * j + 40);
    const int S = (j == 0) ? 0 : (j == 1) ? 72 : (16 * j * j + 24 * j + 32);
    return 32 * S + (t & 1) * 16 * V;
}

// ---------------------------------------------------------------------------
// fused r19 (= r17 logic, third submit after two container-level infra
// failures; audit found no hang/OOB path.  Hedge: outer chunk loop no
// longer force-unrolled -- half the phase-1 code size, identical math).
// r16 post-mortem: occupancy rose 26.7->37.6 as predicted but dur only
// -2.5us -> phase-2 drain was small; real cost is the LDS pipe (~48% busy:
// 1536 phase-1 B-frag ds_read_b128 = 18k cy/CU, 16x redundant W reads).
// Phase 1 uses mfma_32x32x16 (2x MACs per B-byte): wave (rb=w&7, ch=w>>3)
// does 32 rows x col-tiles {ch,2+ch,4+ch} (K/q/V) -> 768 B-reads.
// Epilogue (K scaled, VT, q-slots) feeds the IDENTICAL phase-2 layouts;
// q-transpose merged into epilogue (barrier B2 removed). Phase 2 = r16.
// ---------------------------------------------------------------------------
__global__ __launch_bounds__(1024, 4) void fused(
    const float* __restrict__ x, const _Float16* __restrict__ WT,
    const _Float16* __restrict__ rpeh, float* __restrict__ out)
{
    __shared__ _Float16 lds[75264];        // 147 KB: K | VT | pool
    __shared__ float rowsumP[2][256];      // 2-slot row-sum partials
    _Float16* Klds = lds;                  // [256][72]
    _Float16* VT   = lds + 18432;          // [64][264]
    _Float16* pool = lds + 35328;          // 39936 halves (W chunks / slots)

    const int tid  = threadIdx.x;
    const int b    = blockIdx.x;
    const int w    = tid >> 6;
    const int lane = tid & 63;
    const int quad = lane >> 4;
    const int l    = lane & 15;
    const int r32  = lane & 31;
    const int l5   = lane >> 5;
    const int rb   = w & 7;                // 32-row block
    const int ch   = w >> 3;               // col half (32 of each of K/q/V)

    union H8 { half8 v; fp16x2 p[4]; };
    const float4* xg = reinterpret_cast<const float4*>(x);
    const size_t xrow = (size_t)(b * 256 + rb * 32 + r32) * 64;  // float4 units

    floatx16 acc[3];                       // j=0:K, 1:q, 2:V (col-tile 2j+ch)
#pragma unroll
    for (int j = 0; j < 3; ++j)
#pragma unroll
        for (int e = 0; e < 16; ++e) acc[j][e] = 0.f;

    // ---- phase 1: proj in 2 K-chunks of 128, 32x32x16 MFMA ---------------
    for (int c = 0; c < 2; ++c) {
        // stage W chunk c: [192][136] (3072 granules / 1024 thr = 3 each)
#pragma unroll
        for (int i = 0; i < 3; ++i) {
            const int gi  = tid + i * 1024;
            const int row = gi >> 4;
            const int g   = gi & 15;
            *(half8*)&pool[row * 136 + g * 8] =
                *(const half8*)(WT + (size_t)row * 256 + c * 128 + g * 8);
        }
        // issue first x half-batch before the barrier (latency hides under it)
        float4 xa[4][2];
#pragma unroll
        for (int s = 0; s < 4; ++s) {
            const size_t base = xrow + c * 32 + s * 4 + l5 * 2;
            xa[s][0] = xg[base];
            xa[s][1] = xg[base + 1];
        }
        __syncthreads();

#pragma unroll
        for (int hb = 0; hb < 2; ++hb) {
            if (hb == 1) {   // load second half-batch
#pragma unroll
                for (int s = 0; s < 4; ++s) {
                    const size_t base = xrow + c * 32 + (4 + s) * 4 + l5 * 2;
                    xa[s][0] = xg[base];
                    xa[s][1] = xg[base + 1];
                }
            }
#pragma unroll
            for (int s = 0; s < 4; ++s) {
                const int ks = hb * 4 + s;
                H8 u;
                u.p[0] = __builtin_amdgcn_cvt_pkrtz(xa[s][0].x, xa[s][0].y);
                u.p[1] = __builtin_amdgcn_cvt_pkrtz(xa[s][0].z, xa[s][0].w);
                u.p[2] = __builtin_amdgcn_cvt_pkrtz(xa[s][1].x, xa[s][1].y);
                u.p[3] = __builtin_amdgcn_cvt_pkrtz(xa[s][1].z, xa[s][1].w);
#pragma unroll
                for (int j = 0; j < 3; ++j) {
                    const half8 bf = *(const half8*)&pool[
                        (size_t)((2 * j + ch) * 32 + r32) * 136 + ks * 16 + l5 * 8];
                    acc[j] = __builtin_amdgcn_mfma_f32_32x32x16_f16(u.v, bf, acc[j], 0, 0, 0);
                }
            }
        }
        __syncthreads();   // chunk readers done (protects restage / slots)
    }

    // ---- epilogue: K (scaled), VT, q-slots -- one barrier ----------------
    {
        const int cb = ch * 32;
        _Float16* sA = pool + slot_off(2 * rb);
        _Float16* sB = pool + slot_off(2 * rb + 1);
        const int Vs = slot_width(2 * rb);     // == slot_width(2*rb+1)
#pragma unroll
        for (int g = 0; g < 4; ++g) {
#pragma unroll
            for (int r = 0; r < 4; ++r) {
                const int reg = g * 4 + r;
                const int row = r + 8 * g + 4 * l5;          // 0..31
                Klds[(rb * 32 + row) * 72 + cb + r32] = (_Float16)(acc[0][reg] * 0.125f);
                _Float16* qs = (row < 16) ? sA : sB;          // g<2 -> sA (uniform)
                qs[(row & 15) * Vs + cb + r32] = (_Float16)acc[1][reg];
            }
            half4 vv;
            vv[0] = (_Float16)acc[2][g * 4 + 0];
            vv[1] = (_Float16)acc[2][g * 4 + 1];
            vv[2] = (_Float16)acc[2][g * 4 + 2];
            vv[3] = (_Float16)acc[2][g * 4 + 3];
            *(half4*)&VT[(size_t)(cb + r32) * 264 + rb * 32 + g * 8 + l5 * 4] = vv;
        }
    }
    if (tid < 512) ((float*)rowsumP)[tid] = 0.f;
    __syncthreads();       // B1: K/VT/q visible; pool slots carry q

    // ---- phase 2: flash, (t, 15-t) paired balance (r16, unchanged) -------
    _Float16* wh = pool + slot_off(w);
    const int Vw = slot_width(w);

    // read q A-frags: own + partner (slot q-region not yet clobbered)
    const half8 qf0 = *(const half8*)&wh[l * Vw + quad * 8];
    const half8 qf1 = *(const half8*)&wh[l * Vw + 32 + quad * 8];
    const int tp = 15 - w;
    _Float16* whp = pool + slot_off(tp);
    const int Vp = slot_width(tp);
    half8 qg0 = qf0, qg1 = qf1;
    if (w < 8) {
        qg0 = *(const half8*)&whp[l * Vp + quad * 8];
        qg1 = *(const half8*)&whp[l * Vp + 32 + quad * 8];
    }
    __syncthreads();       // B3: q consumed everywhere; slots writable

    // ---- phase 2b: pos scores (skewed scatter), balanced -----------------
    const int jmaxo = (w < 8) ? w : 8;     // own bands j=0..jmaxo
#pragma unroll
    for (int j = 0; j < 9; ++j) {
        if (j <= jmaxo) {
            const int dt = j + 15 - w;
            const _Float16* rp = rpeh + (size_t)(dt * 16 + l) * HH + quad * 8;
            const half8 bf0 = *(const half8*)rp;
            const half8 bf1 = *(const half8*)(rp + 32);
            floatx4 z = {0.f, 0.f, 0.f, 0.f};
            z = __builtin_amdgcn_mfma_f32_16x16x32_f16(qf0, bf0, z, 0, 0, 0);
            const floatx4 pacc = __builtin_amdgcn_mfma_f32_16x16x32_f16(qf1, bf1, z, 0, 0, 0);
            if (j == 0) {
#pragma unroll
                for (int r = 0; r < 4; ++r) {
                    const int row = quad * 4 + r;
                    const int s   = l + row - 15;
                    if (s >= 0) wh[row * Vw + s] = (_Float16)pacc[r];
                }
            } else {
#pragma unroll
                for (int r = 0; r < 4; ++r) {
                    const int row = quad * 4 + r;
                    wh[row * Vw + 16 * j + l + row - 15] = (_Float16)pacc[r];
                }
            }
        }
    }
    if (w < 8) {                            // partner bands j=9..15-w (s>=129)
#pragma unroll
        for (int j = 9; j < 16; ++j) {
            if (j <= 15 - w) {
                const int dt = j + w;
                const _Float16* rp = rpeh + (size_t)(dt * 16 + l) * HH + quad * 8;
                const half8 bf0 = *(const half8*)rp;
                const half8 bf1 = *(const half8*)(rp + 32);
                floatx4 z = {0.f, 0.f, 0.f, 0.f};
                z = __builtin_amdgcn_mfma_f32_16x16x32_f16(qg0, bf0, z, 0, 0, 0);
                const floatx4 pacc = __builtin_amdgcn_mfma_f32_16x16x32_f16(qg1, bf1, z, 0, 0, 0);
#pragma unroll
                for (int r = 0; r < 4; ++r) {
                    const int row = quad * 4 + r;
                    whp[row * Vp + 16 * j + l + row - 15] = (_Float16)pacc[r];
                }
            }
        }
    }
    __syncthreads();       // B4: all pos bands written

    // ---- phase 2c: content scores + exp + partial row-sums ---------------
    {
        float sumsA[4] = {0.f, 0.f, 0.f, 0.f};
#pragma unroll
        for (int st = 0; st < 9; ++st) {
            if (st <= jmaxo) {
                const _Float16* kp = &Klds[(st * 16 + l) * 72 + quad * 8];
                const half8 kf0 = *(const half8*)kp;
                const half8 kf1 = *(const half8*)(kp + 32);
                floatx4 z = {0.f, 0.f, 0.f, 0.f};
                z = __builtin_amdgcn_mfma_f32_16x16x32_f16(qf0, kf0, z, 0, 0, 0);
                const floatx4 sacc = __builtin_amdgcn_mfma_f32_16x16x32_f16(qf1, kf1, z, 0, 0, 0);
                const int s = l + 16 * st;
                if (st == w) {             // own diagonal (only w<=8)
#pragma unroll
                    for (int r = 0; r < 4; ++r) {
                        const int row = quad * 4 + r;
                        float e = 0.f;
                        if (l <= row) e = __expf(sacc[r] + (float)wh[row * Vw + s]);
                        sumsA[r] += e;
                        wh[row * Vw + s] = (_Float16)e;
                    }
                    if ((w & 1) == 0) {    // zero strip covering PV read window
                        const int s2 = l + 16 * (st + 1);
#pragma unroll
                        for (int r = 0; r < 4; ++r) wh[(quad * 4 + r) * Vw + s2] = (_Float16)0.f;
                    }
                } else {
#pragma unroll
                    for (int r = 0; r < 4; ++r) {
                        const int row = quad * 4 + r;
                        const float e = __expf(sacc[r] + (float)wh[row * Vw + s]);
                        sumsA[r] += e;
                        wh[row * Vw + s] = (_Float16)e;
                    }
                }
            }
        }
#pragma unroll
        for (int r = 0; r < 4; ++r) {
            float sv = sumsA[r];
            sv += __shfl_xor(sv, 1);
            sv += __shfl_xor(sv, 2);
            sv += __shfl_xor(sv, 4);
            sv += __shfl_xor(sv, 8);
            if (l == 0) rowsumP[0][16 * w + quad * 4 + r] = sv;
        }
    }
    if (w < 8) {                            // partner tiles st=9..15-w
        float sumsB[4] = {0.f, 0.f, 0.f, 0.f};
#pragma unroll
        for (int st = 9; st < 16; ++st) {
            if (st <= 15 - w) {
                const _Float16* kp = &Klds[(st * 16 + l) * 72 + quad * 8];
                const half8 kf0 = *(const half8*)kp;
                const half8 kf1 = *(const half8*)(kp + 32);
                floatx4 z = {0.f, 0.f, 0.f, 0.f};
                z = __builtin_amdgcn_mfma_f32_16x16x32_f16(qg0, kf0, z, 0, 0, 0);
                const floatx4 sacc = __builtin_amdgcn_mfma_f32_16x16x32_f16(qg1, kf1, z, 0, 0, 0);
                const int s = l + 16 * st;
                if (st == tp) {            // partner diagonal
#pragma unroll
                    for (int r = 0; r < 4; ++r) {
                        const int row = quad * 4 + r;
                        float e = 0.f;
                        if (l <= row) e = __expf(sacc[r] + (float)whp[row * Vp + s]);
                        sumsB[r] += e;
                        whp[row * Vp + s] = (_Float16)e;
                    }
                    if ((tp & 1) == 0) {
                        const int s2 = l + 16 * (st + 1);
#pragma unroll
                        for (int r = 0; r < 4; ++r) whp[(quad * 4 + r) * Vp + s2] = (_Float16)0.f;
                    }
                } else {
#pragma unroll
                    for (int r = 0; r < 4; ++r) {
                        const int row = quad * 4 + r;
                        const float e = __expf(sacc[r] + (float)whp[row * Vp + s]);
                        sumsB[r] += e;
                        whp[row * Vp + s] = (_Float16)e;
                    }
                }
            }
        }
#pragma unroll
        for (int r = 0; r < 4; ++r) {
            float sv = sumsB[r];
            sv += __shfl_xor(sv, 1);
            sv += __shfl_xor(sv, 2);
            sv += __shfl_xor(sv, 4);
            sv += __shfl_xor(sv, 8);
            if (l == 0) rowsumP[1][16 * tp + quad * 4 + r] = sv;
        }
    }
    __syncthreads();       // B5: exp-weights + row-sums complete

    // ---- phase 2d: PV, paired (t1, 15-t1) x 2 head-tiles -> 18 MFMA/wave -
    {
        const int t1 = w >> 1;
        const int hb = (w & 1) << 1;
#pragma unroll
        for (int sel = 0; sel < 2; ++sel) {
            const int tt = sel ? (15 - t1) : t1;
            const _Float16* ws = pool + slot_off(tt);
            const int Vt    = slot_width(tt);
            const int cmaxt = tt >> 1;
            float inv[4];
#pragma unroll
            for (int r = 0; r < 4; ++r) {
                const int row = 16 * tt + quad * 4 + r;
                inv[r] = 1.0f / (rowsumP[0][row] + rowsumP[1][row]);
            }
            floatx4 o0 = {0.f, 0.f, 0.f, 0.f};
            floatx4 o1 = {0.f, 0.f, 0.f, 0.f};
#pragma unroll
            for (int c = 0; c < 8; ++c) {
                if (c <= cmaxt) {
                    const half8 af  = *(const half8*)&ws[l * Vt + c * 32 + quad * 8];
                    const half8 vf0 = *(const half8*)&VT[((hb + 0) * 16 + l) * 264 + c * 32 + quad * 8];
                    const half8 vf1 = *(const half8*)&VT[((hb + 1) * 16 + l) * 264 + c * 32 + quad * 8];
                    o0 = __builtin_amdgcn_mfma_f32_16x16x32_f16(af, vf0, o0, 0, 0, 0);
                    o1 = __builtin_amdgcn_mfma_f32_16x16x32_f16(af, vf1, o1, 0, 0, 0);
                }
            }
#pragma unroll
            for (int r = 0; r < 4; ++r) {
                const int t = 16 * tt + quad * 4 + r;
                out[(size_t)(b * TT + t) * HH + (hb + 0) * 16 + l] = o0[r] * inv[r];
                out[(size_t)(b * TT + t) * HH + (hb + 1) * 16 + l] = o1[r] * inv[r];
            }
        }
    }
}

extern "C" void kernel_launch(void* const* d_in, const int* in_sizes, int n_in,
                              void* d_out, int out_size, void* d_ws, size_t ws_size,
                              hipStream_t stream) {
    const float* x   = (const float*)d_in[0];
    const float* Wk  = (const float*)d_in[1];
    const float* Wq  = (const float*)d_in[2];
    const float* Wv  = (const float*)d_in[3];
    const float* rpe = (const float*)d_in[4];
    float* out = (float*)d_out;

    _Float16* rpeh = (_Float16*)d_ws;              // [256][64]
    _Float16* WT   = rpeh + 256 * HH;              // [192][256]

    prep<<<dim3(256), dim3(256), 0, stream>>>(rpe, Wk, Wq, Wv, rpeh, WT);
    fused<<<dim3(BB), dim3(1024), 0, stream>>>(x, WT, rpeh, out);
}

// Round 5
// 123.762 us; speedup vs baseline: 1.0625x; 1.0625x over previous
//
#include <hip/hip_runtime.h>

#define BB 256
#define TT 256
#define CC 256
#define HH 64

typedef _Float16 half8 __attribute__((ext_vector_type(8)));
typedef _Float16 half4 __attribute__((ext_vector_type(4)));
typedef __fp16 fp16x2 __attribute__((ext_vector_type(2)));
typedef float floatx4 __attribute__((ext_vector_type(4)));

// ---------------------------------------------------------------------------
// prep: blocks 0..63   -> rpeh[i] = (f16) rpe[i]  (rows 0..255)
//       blocks 64..255 -> WT[(w*64+n)][k] = (f16) W_w[k][n]
// ---------------------------------------------------------------------------
__global__ __launch_bounds__(256) void prep(
    const float* __restrict__ rpe,
    const float* __restrict__ Wk, const float* __restrict__ Wq, const float* __restrict__ Wv,
    _Float16* __restrict__ rpeh, _Float16* __restrict__ WT)
{
    const int bid = blockIdx.x, tid = threadIdx.x;
    if (bid < 64) {
        const int i = bid * 256 + tid;
        rpeh[i] = (_Float16)rpe[i];
    } else {
        const int wsel = (bid - 64) >> 6;          // 0=k, 1=q, 2=v
        const int n    = (bid - 64) & 63;
        const float* W = wsel == 0 ? Wk : (wsel == 1 ? Wq : Wv);
        WT[(size_t)(wsel * 64 + n) * 256 + tid] = (_Float16)W[tid * HH + n];
    }
}

// per-tile exp-weight slot pool: pair j = t>>1 shares width V_j
__device__ __forceinline__ int slot_width(int t) {
    const int j = t >> 1;
    return (j < 2) ? 72 : (32 * j + 40);
}
__device__ __forceinline__ int slot_off(int t) {      // halves, rel. to pool
    const int j = t >> 1;
    const int V = (j < 2) ? 72 : (32 * j + 40);
    const int S = (j == 0) ? 0 : (j == 1) ? 72 : (16 * j * j + 24 * j + 32);
    return 32 * S + (t & 1) * 16 * V;
}

// ---------------------------------------------------------------------------
// fused r20: r16 structure (measured 43.4us) with barrier B4 REMOVED.
// r19 post-mortem: 32x32 phase-1 halved LDS B-reads + conflicts (2.37M->
// 0.80M) yet +3us -- MFMA busy identical, VALU rose (x loads + cvt doubled).
// => neither LDS pipe nor conflicts are critical; kernel is ~82% stall
// (dependency/barrier latency at 4 waves/SIMD).  Dependency re-derivation:
// every pos band a wave exponentiates is written BY THAT WAVE (tiles t<8:
// bands 0..t by wave t; tiles t>=8: bands 0..8 exp'd by wave t, bands 9..t
// incl. diagonal exp'd by wave 15-t -- all self-written).  Cross-wave pos
// writes land in disjoint s-ranges; rowsums read only after B5.  So B4
// synchronized nothing: removing it merges pos+content+exp into one
// barrier-free region (rpe global loads || K ds_reads || MFMA || exp).
// ---------------------------------------------------------------------------
__global__ __launch_bounds__(1024, 4) void fused(
    const float* __restrict__ x, const _Float16* __restrict__ WT,
    const _Float16* __restrict__ rpeh, float* __restrict__ out)
{
    __shared__ _Float16 lds[75264];        // 147 KB: K | VT | pool
    __shared__ float rowsumP[2][256];      // 2-slot row-sum partials
    _Float16* Klds = lds;                  // [256][72]
    _Float16* VT   = lds + 18432;          // [64][264]
    _Float16* pool = lds + 35328;          // 39936 halves (W chunks / slots)

    const int tid  = threadIdx.x;
    const int b    = blockIdx.x;
    const int w    = tid >> 6;
    const int lane = tid & 63;
    const int quad = lane >> 4;
    const int l    = lane & 15;

    union H8 { half8 v; fp16x2 p[4]; };
    const float4* xg = reinterpret_cast<const float4*>(x);
    const int row0g = b * 256 + w * 16;    // wave's 16 x-rows

    floatx4 acc[12];
#pragma unroll
    for (int nt = 0; nt < 12; ++nt) acc[nt] = (floatx4){0.f, 0.f, 0.f, 0.f};

    // ---- phase 1: proj in 2 K-chunks of 128 ------------------------------
#pragma unroll
    for (int c = 0; c < 2; ++c) {
        // stage W chunk c: [192][136] (3072 granules / 1024 thr = 3 each)
#pragma unroll
        for (int i = 0; i < 3; ++i) {
            const int gi  = tid + i * 1024;
            const int row = gi >> 4;
            const int g   = gi & 15;
            *(half8*)&pool[row * 136 + g * 8] =
                *(const half8*)(WT + (size_t)row * 256 + c * 128 + g * 8);
        }
        __syncthreads();

        // prefetch all 8 x float4 for this chunk (MLP), then cvt+MFMA
        float4 xa[4][2];
#pragma unroll
        for (int kk = 0; kk < 4; ++kk) {
            const size_t base = (size_t)(row0g + l) * 64 + c * 32 + kk * 8 + quad * 2;
            xa[kk][0] = xg[base];
            xa[kk][1] = xg[base + 1];
        }
#pragma unroll
        for (int kk = 0; kk < 4; ++kk) {
            H8 u;
            u.p[0] = __builtin_amdgcn_cvt_pkrtz(xa[kk][0].x, xa[kk][0].y);
            u.p[1] = __builtin_amdgcn_cvt_pkrtz(xa[kk][0].z, xa[kk][0].w);
            u.p[2] = __builtin_amdgcn_cvt_pkrtz(xa[kk][1].x, xa[kk][1].y);
            u.p[3] = __builtin_amdgcn_cvt_pkrtz(xa[kk][1].z, xa[kk][1].w);
#pragma unroll
            for (int nt = 0; nt < 12; ++nt) {
                const half8 bf = *(const half8*)&pool[(nt * 16 + l) * 136 + kk * 32 + quad * 8];
                acc[nt] = __builtin_amdgcn_mfma_f32_16x16x32_f16(u.v, bf, acc[nt], 0, 0, 0);
            }
        }
        __syncthreads();   // chunk readers done (protects restage / slots)
    }

    // ---- epilogue: K (scaled) and VT into LDS ----------------------------
    {
        const int trw = w * 16;
#pragma unroll
        for (int nt = 0; nt < 4; ++nt) {
#pragma unroll
            for (int r = 0; r < 4; ++r)
                Klds[(trw + quad * 4 + r) * 72 + nt * 16 + l] = (_Float16)(acc[nt][r] * 0.125f);
            half4 vv;
            vv[0] = (_Float16)acc[nt + 8][0];
            vv[1] = (_Float16)acc[nt + 8][1];
            vv[2] = (_Float16)acc[nt + 8][2];
            vv[3] = (_Float16)acc[nt + 8][3];
            *(half4*)&VT[(nt * 16 + l) * 264 + trw + quad * 4] = vv;
        }
    }
    if (tid < 512) ((float*)rowsumP)[tid] = 0.f;
    __syncthreads();       // B1: K/VT visible; pool free for slots

    // ---- phase 2a: q transpose into own slot -----------------------------
    _Float16* wh = pool + slot_off(w);
    const int Vw = slot_width(w);
#pragma unroll
    for (int nt = 0; nt < 4; ++nt)
#pragma unroll
        for (int r = 0; r < 4; ++r)
            wh[(quad * 4 + r) * Vw + nt * 16 + l] = (_Float16)acc[nt + 4][r];
    __syncthreads();       // B2: all q slots written

    // read q A-frags: own + partner (partner slot q-region not yet clobbered)
    const half8 qf0 = *(const half8*)&wh[l * Vw + quad * 8];
    const half8 qf1 = *(const half8*)&wh[l * Vw + 32 + quad * 8];
    const int tp = 15 - w;
    _Float16* whp = pool + slot_off(tp);
    const int Vp = slot_width(tp);
    half8 qg0 = qf0, qg1 = qf1;
    if (w < 8) {
        qg0 = *(const half8*)&whp[l * Vp + quad * 8];
        qg1 = *(const half8*)&whp[l * Vp + 32 + quad * 8];
    }
    __syncthreads();       // B3: q consumed everywhere; slots writable

    // ---- phase 2b: pos scores (skewed scatter), balanced -----------------
    const int jmaxo = (w < 8) ? w : 8;     // own bands j=0..jmaxo
#pragma unroll
    for (int j = 0; j < 9; ++j) {
        if (j <= jmaxo) {
            const int dt = j + 15 - w;
            const _Float16* rp = rpeh + (size_t)(dt * 16 + l) * HH + quad * 8;
            const half8 bf0 = *(const half8*)rp;
            const half8 bf1 = *(const half8*)(rp + 32);
            floatx4 z = {0.f, 0.f, 0.f, 0.f};
            z = __builtin_amdgcn_mfma_f32_16x16x32_f16(qf0, bf0, z, 0, 0, 0);
            const floatx4 pacc = __builtin_amdgcn_mfma_f32_16x16x32_f16(qf1, bf1, z, 0, 0, 0);
            if (j == 0) {
#pragma unroll
                for (int r = 0; r < 4; ++r) {
                    const int row = quad * 4 + r;
                    const int s   = l + row - 15;
                    if (s >= 0) wh[row * Vw + s] = (_Float16)pacc[r];
                }
            } else {
#pragma unroll
                for (int r = 0; r < 4; ++r) {
                    const int row = quad * 4 + r;
                    wh[row * Vw + 16 * j + l + row - 15] = (_Float16)pacc[r];
                }
            }
        }
    }
    if (w < 8) {                            // partner bands j=9..15-w (s>=129)
#pragma unroll
        for (int j = 9; j < 16; ++j) {
            if (j <= 15 - w) {
                const int dt = j + w;
                const _Float16* rp = rpeh + (size_t)(dt * 16 + l) * HH + quad * 8;
                const half8 bf0 = *(const half8*)rp;
                const half8 bf1 = *(const half8*)(rp + 32);
                floatx4 z = {0.f, 0.f, 0.f, 0.f};
                z = __builtin_amdgcn_mfma_f32_16x16x32_f16(qg0, bf0, z, 0, 0, 0);
                const floatx4 pacc = __builtin_amdgcn_mfma_f32_16x16x32_f16(qg1, bf1, z, 0, 0, 0);
#pragma unroll
                for (int r = 0; r < 4; ++r) {
                    const int row = quad * 4 + r;
                    whp[row * Vp + 16 * j + l + row - 15] = (_Float16)pacc[r];
                }
            }
        }
    }
    // NOTE: no barrier here (was B4).  Every pos band exp'd below is written
    // by this same wave above; cross-wave pos writes are in disjoint s-ranges.

    // ---- phase 2c: content scores + exp + partial row-sums ---------------
    {
        float sumsA[4] = {0.f, 0.f, 0.f, 0.f};
#pragma unroll
        for (int st = 0; st < 9; ++st) {
            if (st <= jmaxo) {
                const _Float16* kp = &Klds[(st * 16 + l) * 72 + quad * 8];
                const half8 kf0 = *(const half8*)kp;
                const half8 kf1 = *(const half8*)(kp + 32);
                floatx4 z = {0.f, 0.f, 0.f, 0.f};
                z = __builtin_amdgcn_mfma_f32_16x16x32_f16(qf0, kf0, z, 0, 0, 0);
                const floatx4 sacc = __builtin_amdgcn_mfma_f32_16x16x32_f16(qf1, kf1, z, 0, 0, 0);
                const int s = l + 16 * st;
                if (st == w) {             // own diagonal (only w<=8)
#pragma unroll
                    for (int r = 0; r < 4; ++r) {
                        const int row = quad * 4 + r;
                        float e = 0.f;
                        if (l <= row) e = __expf(sacc[r] + (float)wh[row * Vw + s]);
                        sumsA[r] += e;
                        wh[row * Vw + s] = (_Float16)e;
                    }
                    if ((w & 1) == 0) {    // zero strip covering PV read window
                        const int s2 = l + 16 * (st + 1);
#pragma unroll
                        for (int r = 0; r < 4; ++r) wh[(quad * 4 + r) * Vw + s2] = (_Float16)0.f;
                    }
                } else {
#pragma unroll
                    for (int r = 0; r < 4; ++r) {
                        const int row = quad * 4 + r;
                        const float e = __expf(sacc[r] + (float)wh[row * Vw + s]);
                        sumsA[r] += e;
                        wh[row * Vw + s] = (_Float16)e;
                    }
                }
            }
        }
#pragma unroll
        for (int r = 0; r < 4; ++r) {
            float sv = sumsA[r];
            sv += __shfl_xor(sv, 1);
            sv += __shfl_xor(sv, 2);
            sv += __shfl_xor(sv, 4);
            sv += __shfl_xor(sv, 8);
            if (l == 0) rowsumP[0][16 * w + quad * 4 + r] = sv;
        }
    }
    if (w < 8) {                            // partner tiles st=9..15-w
        float sumsB[4] = {0.f, 0.f, 0.f, 0.f};
#pragma unroll
        for (int st = 9; st < 16; ++st) {
            if (st <= 15 - w) {
                const _Float16* kp = &Klds[(st * 16 + l) * 72 + quad * 8];
                const half8 kf0 = *(const half8*)kp;
                const half8 kf1 = *(const half8*)(kp + 32);
                floatx4 z = {0.f, 0.f, 0.f, 0.f};
                z = __builtin_amdgcn_mfma_f32_16x16x32_f16(qg0, kf0, z, 0, 0, 0);
                const floatx4 sacc = __builtin_amdgcn_mfma_f32_16x16x32_f16(qg1, kf1, z, 0, 0, 0);
                const int s = l + 16 * st;
                if (st == tp) {            // partner diagonal
#pragma unroll
                    for (int r = 0; r < 4; ++r) {
                        const int row = quad * 4 + r;
                        float e = 0.f;
                        if (l <= row) e = __expf(sacc[r] + (float)whp[row * Vp + s]);
                        sumsB[r] += e;
                        whp[row * Vp + s] = (_Float16)e;
                    }
                    if ((tp & 1) == 0) {
                        const int s2 = l + 16 * (st + 1);
#pragma unroll
                        for (int r = 0; r < 4; ++r) whp[(quad * 4 + r) * Vp + s2] = (_Float16)0.f;
                    }
                } else {
#pragma unroll
                    for (int r = 0; r < 4; ++r) {
                        const int row = quad * 4 + r;
                        const float e = __expf(sacc[r] + (float)whp[row * Vp + s]);
                        sumsB[r] += e;
                        whp[row * Vp + s] = (_Float16)e;
                    }
                }
            }
        }
#pragma unroll
        for (int r = 0; r < 4; ++r) {
            float sv = sumsB[r];
            sv += __shfl_xor(sv, 1);
            sv += __shfl_xor(sv, 2);
            sv += __shfl_xor(sv, 4);
            sv += __shfl_xor(sv, 8);
            if (l == 0) rowsumP[1][16 * tp + quad * 4 + r] = sv;
        }
    }
    __syncthreads();       // B5: exp-weights + row-sums complete

    // ---- phase 2d: PV, paired (t1, 15-t1) x 2 head-tiles -> 18 MFMA/wave -
    {
        const int t1 = w >> 1;
        const int hb = (w & 1) << 1;
#pragma unroll
        for (int sel = 0; sel < 2; ++sel) {
            const int tt = sel ? (15 - t1) : t1;
            const _Float16* ws = pool + slot_off(tt);
            const int Vt    = slot_width(tt);
            const int cmaxt = tt >> 1;
            float inv[4];
#pragma unroll
            for (int r = 0; r < 4; ++r) {
                const int row = 16 * tt + quad * 4 + r;
                inv[r] = 1.0f / (rowsumP[0][row] + rowsumP[1][row]);
            }
            floatx4 o0 = {0.f, 0.f, 0.f, 0.f};
            floatx4 o1 = {0.f, 0.f, 0.f, 0.f};
#pragma unroll
            for (int c = 0; c < 8; ++c) {
                if (c <= cmaxt) {
                    const half8 af  = *(const half8*)&ws[l * Vt + c * 32 + quad * 8];
                    const half8 vf0 = *(const half8*)&VT[((hb + 0) * 16 + l) * 264 + c * 32 + quad * 8];
                    const half8 vf1 = *(const half8*)&VT[((hb + 1) * 16 + l) * 264 + c * 32 + quad * 8];
                    o0 = __builtin_amdgcn_mfma_f32_16x16x32_f16(af, vf0, o0, 0, 0, 0);
                    o1 = __builtin_amdgcn_mfma_f32_16x16x32_f16(af, vf1, o1, 0, 0, 0);
                }
            }
#pragma unroll
            for (int r = 0; r < 4; ++r) {
                const int t = 16 * tt + quad * 4 + r;
                out[(size_t)(b * TT + t) * HH + (hb + 0) * 16 + l] = o0[r] * inv[r];
                out[(size_t)(b * TT + t) * HH + (hb + 1) * 16 + l] = o1[r] * inv[r];
            }
        }
    }
}

extern "C" void kernel_launch(void* const* d_in, const int* in_sizes, int n_in,
                              void* d_out, int out_size, void* d_ws, size_t ws_size,
                              hipStream_t stream) {
    const float* x   = (const float*)d_in[0];
    const float* Wk  = (const float*)d_in[1];
    const float* Wq  = (const float*)d_in[2];
    const float* Wv  = (const float*)d_in[3];
    const float* rpe = (const float*)d_in[4];
    float* out = (float*)d_out;

    _Float16* rpeh = (_Float16*)d_ws;              // [256][64]
    _Float16* WT   = rpeh + 256 * HH;              // [192][256]

    prep<<<dim3(256), dim3(256), 0, stream>>>(rpe, Wk, Wq, Wv, rpeh, WT);
    fused<<<dim3(BB), dim3(1024), 0, stream>>>(x, WT, rpeh, out);
}